// Round 4
// baseline (65.984 us; speedup 1.0000x reference)
//
#include <hip/hip_runtime.h>

#define BB 8
#define SS 4096
#define NN 1024
#define DD 1024
#define NUM_WIDTH 64
#define WIDTH_DIM 64
#define OUTD (DD + WIDTH_DIM)   // 1088
#define NSPAN (BB * NN)         // 8192
#define NBUCK 128               // per-batch start buckets (start >> 5)
#define NBINS (BB * NBUCK)      // 1024

// ---- fused counting sort: init + hist + scan + scatter in ONE block ----
__global__ __launch_bounds__(1024) void sort_kernel(const int* __restrict__ idx,
                                                    int* __restrict__ perm) {
    __shared__ int lds[NBINS];
    int tid = threadIdx.x;
    lds[tid] = 0;
    __syncthreads();

    // histogram (8 spans per thread)
    for (int i = tid; i < NSPAN; i += 1024) {
        int start = idx[i * 2];
        int b = i >> 10;
        int s0 = start > 0 ? start : 0;
        if (s0 > SS - 1) s0 = SS - 1;
        atomicAdd(&lds[b * NBUCK + (s0 >> 5)], 1);
    }
    __syncthreads();

    // Hillis-Steele inclusive scan over 1024 bins
    for (int off = 1; off < NBINS; off <<= 1) {
        int add = (tid >= off) ? lds[tid - off] : 0;
        __syncthreads();
        lds[tid] += add;
        __syncthreads();
    }
    // convert to exclusive
    int ex = (tid > 0) ? lds[tid - 1] : 0;
    __syncthreads();
    lds[tid] = ex;
    __syncthreads();

    // scatter
    for (int i = tid; i < NSPAN; i += 1024) {
        int start = idx[i * 2];
        int b = i >> 10;
        int s0 = start > 0 ? start : 0;
        if (s0 > SS - 1) s0 = SS - 1;
        int pos = atomicAdd(&lds[b * NBUCK + (s0 >> 5)], 1);
        perm[pos] = i;
    }
}

// ---- span kernel: ONE WAVE PER SPAN, no LDS, no barriers ----
// 4 spans per 256-thread block; online softmax, 2-row unrolled.
__global__ __launch_bounds__(256) void span_kernel(const float* __restrict__ seq,
                                                   const int* __restrict__ idx,
                                                   const float* __restrict__ w,
                                                   const float* __restrict__ wemb,
                                                   const int* __restrict__ perm,
                                                   float* __restrict__ out) {
    int wave = threadIdx.x >> 6;
    int lane = threadIdx.x & 63;
    // XCD-chunked swizzle over sorted span order (2048 blocks, 8 XCDs)
    int slot = ((blockIdx.x & 7) * (2048 / 8) + (blockIdx.x >> 3)) * 4 + wave;
    int bn = perm[slot];
    int b  = bn >> 10;

    int start = idx[bn * 2 + 0];
    int end   = idx[bn * 2 + 1];
    int s0 = start > 0 ? start : 0;
    int e0 = end < (SS - 1) ? end : (SS - 1);
    int L  = (start >= 0 && end >= start) ? (e0 - s0 + 1) : 0;
    if (L < 0) L = 0;
    if (L > 32) L = 32;

    const float4* s4 = (const float4*)(seq + ((long long)b * SS + s0) * DD);
    const float4* w4 = (const float4*)w;
    float4 wr0 = w4[lane], wr1 = w4[64 + lane], wr2 = w4[128 + lane], wr3 = w4[192 + lane];

    float m = -INFINITY, Z = 0.f;
    float4 acc0 = make_float4(0.f, 0.f, 0.f, 0.f);
    float4 acc1 = acc0, acc2 = acc0, acc3 = acc0;

    int r = 0;
    for (; r + 2 <= L; r += 2) {
        const float4* rowA = s4 + (long long)r * (DD / 4);
        const float4* rowB = rowA + (DD / 4);
        float4 a0 = rowA[lane], a1 = rowA[64 + lane], a2 = rowA[128 + lane], a3 = rowA[192 + lane];
        float4 b0 = rowB[lane], b1 = rowB[64 + lane], b2 = rowB[128 + lane], b3 = rowB[192 + lane];
        float dA = a0.x * wr0.x + a0.y * wr0.y + a0.z * wr0.z + a0.w * wr0.w
                 + a1.x * wr1.x + a1.y * wr1.y + a1.z * wr1.z + a1.w * wr1.w
                 + a2.x * wr2.x + a2.y * wr2.y + a2.z * wr2.z + a2.w * wr2.w
                 + a3.x * wr3.x + a3.y * wr3.y + a3.z * wr3.z + a3.w * wr3.w;
        float dB = b0.x * wr0.x + b0.y * wr0.y + b0.z * wr0.z + b0.w * wr0.w
                 + b1.x * wr1.x + b1.y * wr1.y + b1.z * wr1.z + b1.w * wr1.w
                 + b2.x * wr2.x + b2.y * wr2.y + b2.z * wr2.z + b2.w * wr2.w
                 + b3.x * wr3.x + b3.y * wr3.y + b3.z * wr3.z + b3.w * wr3.w;
        #pragma unroll
        for (int d = 32; d >= 1; d >>= 1) {
            dA += __shfl_xor(dA, d, 64);
            dB += __shfl_xor(dB, d, 64);
        }
        float mn = fmaxf(m, fmaxf(dA, dB));
        float f  = __expf(m - mn);            // m==-inf -> 0, zeroes stale state
        float eA = __expf(dA - mn);
        float eB = __expf(dB - mn);
        Z = Z * f + eA + eB;
        acc0.x = acc0.x * f + eA * a0.x + eB * b0.x;
        acc0.y = acc0.y * f + eA * a0.y + eB * b0.y;
        acc0.z = acc0.z * f + eA * a0.z + eB * b0.z;
        acc0.w = acc0.w * f + eA * a0.w + eB * b0.w;
        acc1.x = acc1.x * f + eA * a1.x + eB * b1.x;
        acc1.y = acc1.y * f + eA * a1.y + eB * b1.y;
        acc1.z = acc1.z * f + eA * a1.z + eB * b1.z;
        acc1.w = acc1.w * f + eA * a1.w + eB * b1.w;
        acc2.x = acc2.x * f + eA * a2.x + eB * b2.x;
        acc2.y = acc2.y * f + eA * a2.y + eB * b2.y;
        acc2.z = acc2.z * f + eA * a2.z + eB * b2.z;
        acc2.w = acc2.w * f + eA * a2.w + eB * b2.w;
        acc3.x = acc3.x * f + eA * a3.x + eB * b3.x;
        acc3.y = acc3.y * f + eA * a3.y + eB * b3.y;
        acc3.z = acc3.z * f + eA * a3.z + eB * b3.z;
        acc3.w = acc3.w * f + eA * a3.w + eB * b3.w;
        m = mn;
    }
    if (r < L) {
        const float4* rowA = s4 + (long long)r * (DD / 4);
        float4 a0 = rowA[lane], a1 = rowA[64 + lane], a2 = rowA[128 + lane], a3 = rowA[192 + lane];
        float dA = a0.x * wr0.x + a0.y * wr0.y + a0.z * wr0.z + a0.w * wr0.w
                 + a1.x * wr1.x + a1.y * wr1.y + a1.z * wr1.z + a1.w * wr1.w
                 + a2.x * wr2.x + a2.y * wr2.y + a2.z * wr2.z + a2.w * wr2.w
                 + a3.x * wr3.x + a3.y * wr3.y + a3.z * wr3.z + a3.w * wr3.w;
        #pragma unroll
        for (int d = 32; d >= 1; d >>= 1)
            dA += __shfl_xor(dA, d, 64);
        float mn = fmaxf(m, dA);
        float f  = __expf(m - mn);
        float eA = __expf(dA - mn);
        Z = Z * f + eA;
        acc0.x = acc0.x * f + eA * a0.x; acc0.y = acc0.y * f + eA * a0.y;
        acc0.z = acc0.z * f + eA * a0.z; acc0.w = acc0.w * f + eA * a0.w;
        acc1.x = acc1.x * f + eA * a1.x; acc1.y = acc1.y * f + eA * a1.y;
        acc1.z = acc1.z * f + eA * a1.z; acc1.w = acc1.w * f + eA * a1.w;
        acc2.x = acc2.x * f + eA * a2.x; acc2.y = acc2.y * f + eA * a2.y;
        acc2.z = acc2.z * f + eA * a2.z; acc2.w = acc2.w * f + eA * a2.w;
        acc3.x = acc3.x * f + eA * a3.x; acc3.y = acc3.y * f + eA * a3.y;
        acc3.z = acc3.z * f + eA * a3.z; acc3.w = acc3.w * f + eA * a3.w;
    }

    float inv = (Z > 0.f) ? 1.0f / Z : 0.f;
    float4* o4 = (float4*)(out + (long long)bn * OUTD);
    float4 o;
    o.x = acc0.x * inv; o.y = acc0.y * inv; o.z = acc0.z * inv; o.w = acc0.w * inv;
    o4[lane] = o;
    o.x = acc1.x * inv; o.y = acc1.y * inv; o.z = acc1.z * inv; o.w = acc1.w * inv;
    o4[64 + lane] = o;
    o.x = acc2.x * inv; o.y = acc2.y * inv; o.z = acc2.z * inv; o.w = acc2.w * inv;
    o4[128 + lane] = o;
    o.x = acc3.x * inv; o.y = acc3.y * inv; o.z = acc3.z * inv; o.w = acc3.w * inv;
    o4[192 + lane] = o;

    // width embedding: 64 lanes, one float each
    int wdt = end - start;
    if (wdt < 0) wdt = 0;
    if (wdt > NUM_WIDTH - 1) wdt = NUM_WIDTH - 1;
    out[(long long)bn * OUTD + DD + lane] = wemb[wdt * WIDTH_DIM + lane];
}

extern "C" void kernel_launch(void* const* d_in, const int* in_sizes, int n_in,
                              void* d_out, int out_size, void* d_ws, size_t ws_size,
                              hipStream_t stream) {
    const float* seq  = (const float*)d_in[0];
    const int*   idx  = (const int*)d_in[1];
    const float* w    = (const float*)d_in[2];
    const float* wemb = (const float*)d_in[4];
    float* out = (float*)d_out;

    int* perm = (int*)d_ws;              // NSPAN ints

    sort_kernel<<<1, 1024, 0, stream>>>(idx, perm);
    span_kernel<<<NSPAN / 4, 256, 0, stream>>>(seq, idx, w, wemb, perm, out);
}

// Round 5
// 47.283 us; speedup vs baseline: 1.3955x; 1.3955x over previous
//
#include <hip/hip_runtime.h>

#define BB 8
#define SS 4096
#define NN 1024
#define DD 1024
#define NUM_WIDTH 64
#define WIDTH_DIM 64
#define OUTD (DD + WIDTH_DIM)   // 1088
#define NSPAN (BB * NN)         // 8192
#define NBUCK 128               // per-batch start buckets (start >> 5)
#define NBINS (BB * NBUCK)      // 1024

// ---- fused counting sort: init + hist + scan + scatter in ONE dispatch ----
__global__ __launch_bounds__(1024) void sort_kernel(const int* __restrict__ idx,
                                                    int* __restrict__ perm) {
    __shared__ int lds[NBINS];
    int tid = threadIdx.x;
    lds[tid] = 0;
    __syncthreads();

    for (int i = tid; i < NSPAN; i += 1024) {
        int start = idx[i * 2];
        int b = i >> 10;
        int s0 = start > 0 ? start : 0;
        if (s0 > SS - 1) s0 = SS - 1;
        atomicAdd(&lds[b * NBUCK + (s0 >> 5)], 1);
    }
    __syncthreads();

    // Hillis-Steele inclusive scan over 1024 bins
    for (int off = 1; off < NBINS; off <<= 1) {
        int add = (tid >= off) ? lds[tid - off] : 0;
        __syncthreads();
        lds[tid] += add;
        __syncthreads();
    }
    int ex = (tid > 0) ? lds[tid - 1] : 0;   // exclusive
    __syncthreads();
    lds[tid] = ex;
    __syncthreads();

    for (int i = tid; i < NSPAN; i += 1024) {
        int start = idx[i * 2];
        int b = i >> 10;
        int s0 = start > 0 ? start : 0;
        if (s0 > SS - 1) s0 = SS - 1;
        int pos = atomicAdd(&lds[b * NBUCK + (s0 >> 5)], 1);
        perm[pos] = i;
    }
}

// ---- fused span kernel: 4 waves per span, single-pass online softmax ----
__global__ __launch_bounds__(256) void span_kernel(const float* __restrict__ seq,
                                                   const int* __restrict__ idx,
                                                   const float* __restrict__ w,
                                                   const float* __restrict__ wemb,
                                                   const int* __restrict__ perm,
                                                   float* __restrict__ out) {
    // XCD-chunked swizzle over the sorted span order -> per-XCD L2 locality.
    int swz = (blockIdx.x & 7) * (NSPAN / 8) + (blockIdx.x >> 3);
    int bn  = perm[swz];
    int b   = bn >> 10;
    int tid = threadIdx.x;
    int wave = tid >> 6;
    int lane = tid & 63;

    int start = idx[bn * 2 + 0];
    int end   = idx[bn * 2 + 1];
    int s0 = start > 0 ? start : 0;
    int e0 = end < (SS - 1) ? end : (SS - 1);
    int L  = (start >= 0 && end >= start) ? (e0 - s0 + 1) : 0;
    if (L < 0) L = 0;
    if (L > 32) L = 32;

    // width embedding early: independent store, overlaps the gather
    if (tid < WIDTH_DIM) {
        int wdt = end - start;
        if (wdt < 0) wdt = 0;
        if (wdt > NUM_WIDTH - 1) wdt = NUM_WIDTH - 1;
        out[(long long)bn * OUTD + DD + tid] = wemb[wdt * WIDTH_DIM + tid];
    }

    __shared__ float lds_acc[4][DD];     // per-wave unscaled accumulators
    __shared__ float lds_m[4], lds_z[4];

    const float4* s4 = (const float4*)(seq + ((long long)b * SS + s0) * DD);
    const float4* w4 = (const float4*)w;
    float4 wr0 = w4[lane], wr1 = w4[64 + lane], wr2 = w4[128 + lane], wr3 = w4[192 + lane];

    float m = -INFINITY, Z = 0.f;
    float4 acc0 = make_float4(0.f, 0.f, 0.f, 0.f);
    float4 acc1 = acc0, acc2 = acc0, acc3 = acc0;

    for (int r = wave; r < L; r += 4) {
        const float4* row = s4 + (long long)r * (DD / 4);
        float4 a0 = row[lane], a1 = row[64 + lane], a2 = row[128 + lane], a3 = row[192 + lane];
        float dot = a0.x * wr0.x + a0.y * wr0.y + a0.z * wr0.z + a0.w * wr0.w
                  + a1.x * wr1.x + a1.y * wr1.y + a1.z * wr1.z + a1.w * wr1.w
                  + a2.x * wr2.x + a2.y * wr2.y + a2.z * wr2.z + a2.w * wr2.w
                  + a3.x * wr3.x + a3.y * wr3.y + a3.z * wr3.z + a3.w * wr3.w;
        #pragma unroll
        for (int d = 32; d >= 1; d >>= 1)
            dot += __shfl_xor(dot, d, 64);
        // dot is wave-uniform; branch below is wave-uniform (no divergence)
        if (dot > m) {
            float f = __expf(m - dot);   // m==-inf -> f=0, zeroes stale state
            Z *= f;
            acc0.x *= f; acc0.y *= f; acc0.z *= f; acc0.w *= f;
            acc1.x *= f; acc1.y *= f; acc1.z *= f; acc1.w *= f;
            acc2.x *= f; acc2.y *= f; acc2.z *= f; acc2.w *= f;
            acc3.x *= f; acc3.y *= f; acc3.z *= f; acc3.w *= f;
            m = dot;
        }
        float e = __expf(dot - m);
        Z += e;
        acc0.x += e * a0.x; acc0.y += e * a0.y; acc0.z += e * a0.z; acc0.w += e * a0.w;
        acc1.x += e * a1.x; acc1.y += e * a1.y; acc1.z += e * a1.z; acc1.w += e * a1.w;
        acc2.x += e * a2.x; acc2.y += e * a2.y; acc2.z += e * a2.z; acc2.w += e * a2.w;
        acc3.x += e * a3.x; acc3.y += e * a3.y; acc3.z += e * a3.z; acc3.w += e * a3.w;
    }

    // per-wave partials -> LDS (unscaled; scale applied during combine)
    if (lane == 0) { lds_m[wave] = m; lds_z[wave] = Z; }
    float4* la = (float4*)lds_acc[wave];
    la[lane] = acc0; la[64 + lane] = acc1; la[128 + lane] = acc2; la[192 + lane] = acc3;
    __syncthreads();

    float m0 = lds_m[0], m1 = lds_m[1], m2 = lds_m[2], m3 = lds_m[3];
    float mg = fmaxf(fmaxf(m0, m1), fmaxf(m2, m3));
    float f0 = (m0 == -INFINITY) ? 0.f : __expf(m0 - mg);
    float f1 = (m1 == -INFINITY) ? 0.f : __expf(m1 - mg);
    float f2 = (m2 == -INFINITY) ? 0.f : __expf(m2 - mg);
    float f3 = (m3 == -INFINITY) ? 0.f : __expf(m3 - mg);
    float Zg = f0 * lds_z[0] + f1 * lds_z[1] + f2 * lds_z[2] + f3 * lds_z[3];
    float inv = (Zg > 0.f) ? 1.0f / Zg : 0.f;

    float4 r0 = ((float4*)lds_acc[0])[tid];
    float4 r1 = ((float4*)lds_acc[1])[tid];
    float4 r2 = ((float4*)lds_acc[2])[tid];
    float4 r3 = ((float4*)lds_acc[3])[tid];
    float4 o;
    o.x = (f0 * r0.x + f1 * r1.x + f2 * r2.x + f3 * r3.x) * inv;
    o.y = (f0 * r0.y + f1 * r1.y + f2 * r2.y + f3 * r3.y) * inv;
    o.z = (f0 * r0.z + f1 * r1.z + f2 * r2.z + f3 * r3.z) * inv;
    o.w = (f0 * r0.w + f1 * r1.w + f2 * r2.w + f3 * r3.w) * inv;

    float4* o4 = (float4*)(out + (long long)bn * OUTD);
    o4[tid] = o;
}

extern "C" void kernel_launch(void* const* d_in, const int* in_sizes, int n_in,
                              void* d_out, int out_size, void* d_ws, size_t ws_size,
                              hipStream_t stream) {
    const float* seq  = (const float*)d_in[0];
    const int*   idx  = (const int*)d_in[1];
    const float* w    = (const float*)d_in[2];
    const float* wemb = (const float*)d_in[4];
    float* out = (float*)d_out;

    int* perm = (int*)d_ws;              // NSPAN ints

    sort_kernel<<<1, 1024, 0, stream>>>(idx, perm);
    span_kernel<<<NSPAN, 256, 0, stream>>>(seq, idx, w, wemb, perm, out);
}